// Round 4
// baseline (2374.725 us; speedup 1.0000x reference)
//
#include <hip/hip_runtime.h>
#include <math.h>

#define B_IMG 64
#define H_ 64
#define W_ 64
#define L_ (H_*W_)
#define C_ 96
#define WSZ 8
#define SSZ 4
#define NH_ 4
#define HD_ 24
#define NT_ 64

// bf16 weight workspace layout (element offsets, 2B each)
#define QKVW_OFF 0
#define PROJW_OFF 27648     // 288*96
#define W1_OFF   36864      // +96*96
#define W2_OFF   73728      // +384*96
#define WTOT     110592     // +96*384

typedef short bf16x8 __attribute__((ext_vector_type(8)));
typedef float f32x4  __attribute__((ext_vector_type(4)));

__device__ __forceinline__ float bf2f(unsigned short u) {
    union { unsigned int i; float f; } c; c.i = ((unsigned int)u) << 16; return c.f;
}
__device__ __forceinline__ unsigned short f2bf(float f) {
    union { float f; unsigned int i; } c; c.f = f;
    return (unsigned short)((c.i + 0x7fffu + ((c.i >> 16) & 1u)) >> 16);  // RNE
}
__device__ __forceinline__ void unpack4(uint2 u, float* f) {
    f[0] = bf2f((unsigned short)(u.x));
    f[1] = bf2f((unsigned short)(u.x >> 16));
    f[2] = bf2f((unsigned short)(u.y));
    f[3] = bf2f((unsigned short)(u.y >> 16));
}
__device__ __forceinline__ void unpack8(uint4 u, float* f) {
    f[0] = bf2f((unsigned short)(u.x)); f[1] = bf2f((unsigned short)(u.x >> 16));
    f[2] = bf2f((unsigned short)(u.y)); f[3] = bf2f((unsigned short)(u.y >> 16));
    f[4] = bf2f((unsigned short)(u.z)); f[5] = bf2f((unsigned short)(u.z >> 16));
    f[6] = bf2f((unsigned short)(u.w)); f[7] = bf2f((unsigned short)(u.w >> 16));
}

// ---------------- Kernel 0: convert weights fp32 -> bf16 into d_ws ----------------
__global__ void k_conv(const float* __restrict__ qkvw, const float* __restrict__ projw,
                       const float* __restrict__ w1, const float* __restrict__ w2,
                       unsigned short* __restrict__ ws16) {
    int i = blockIdx.x * 256 + threadIdx.x;
    if (i >= WTOT) return;
    float v;
    if (i < PROJW_OFF)      v = qkvw[i];
    else if (i < W1_OFF)    v = projw[i - PROJW_OFF];
    else if (i < W2_OFF)    v = w1[i - W1_OFF];
    else                    v = w2[i - W2_OFF];
    ws16[i] = f2bf(v);
}

// ---------------- Kernel 1: LN1 + shifted-window attention + proj + residual ----------------
// one block per window; wave w = head w in the attention phase.
// LDS ~49.5 KB -> 3 blocks/CU (12 waves/CU).
__global__ __launch_bounds__(256, 3)
void k_attn(const float* __restrict__ x,
            const float* __restrict__ g1, const float* __restrict__ b1,
            const unsigned short* __restrict__ wsw,
            const float* __restrict__ qkvb,
            const float* __restrict__ rpbt,
            const float* __restrict__ projb,
            float* __restrict__ xmid)
{
    const int wid = blockIdx.x;
    const int b = wid >> 6, whi = (wid >> 3) & 7, wwi = wid & 7;
    const int tid = threadIdx.x;

    __shared__ __align__(16) unsigned short hbn[NT_][100];      // LN out bf16; later attn-out (12.8KB)
    __shared__ __align__(16) unsigned short qb[NH_][NT_][26];   // 13.3KB (52B rows, 4-aligned)
    __shared__ __align__(16) unsigned short kb[NH_][NT_][24];   // 12.0KB (48B rows, 16-aligned)
    __shared__ __align__(16) unsigned short vb[NH_][NT_][24];   // 12.0KB

    // ---- P1: LayerNorm -> hbn (bf16) ----
    {
        const int tok = tid >> 2, q = tid & 3;
        const int i = tok >> 3, j = tok & 7;
        const int sr = (whi*WSZ + i + SSZ) & (H_-1);
        const int sc = (wwi*WSZ + j + SSZ) & (W_-1);
        const float* row = x + ((size_t)b*L_ + sr*W_ + sc) * C_;
        float v[24];
        float s = 0.f, s2 = 0.f;
#pragma unroll
        for (int m = 0; m < 6; ++m) {
            float4 f = ((const float4*)row)[q + 4*m];
            v[4*m+0]=f.x; v[4*m+1]=f.y; v[4*m+2]=f.z; v[4*m+3]=f.w;
            s  += f.x+f.y+f.z+f.w;
            s2 += f.x*f.x+f.y*f.y+f.z*f.z+f.w*f.w;
        }
        s  += __shfl_xor(s, 1);  s  += __shfl_xor(s, 2);
        s2 += __shfl_xor(s2, 1); s2 += __shfl_xor(s2, 2);
        const float mu = s * (1.f/96.f);
        const float rstd = rsqrtf(s2*(1.f/96.f) - mu*mu + 1e-5f);
#pragma unroll
        for (int m = 0; m < 6; ++m) {
            const int c0 = 4*(q + 4*m);
            float o0 = (v[4*m+0]-mu)*rstd*g1[c0+0] + b1[c0+0];
            float o1 = (v[4*m+1]-mu)*rstd*g1[c0+1] + b1[c0+1];
            float o2 = (v[4*m+2]-mu)*rstd*g1[c0+2] + b1[c0+2];
            float o3 = (v[4*m+3]-mu)*rstd*g1[c0+3] + b1[c0+3];
            uint2 u;
            u.x = (unsigned int)f2bf(o0) | ((unsigned int)f2bf(o1) << 16);
            u.y = (unsigned int)f2bf(o2) | ((unsigned int)f2bf(o3) << 16);
            *(uint2*)&hbn[tok][c0] = u;
        }
    }
    __syncthreads();

    // ---- P2: QKV GEMM (fp32 FMA on bf16 operands) -> qb/kb/vb ----
    {
        const int sub = tid & 63, wv = tid >> 6;
        const int tg = sub >> 2, dg = sub & 3;   // 16 token-groups x 4 d-groups
#pragma unroll
        for (int it = 0; it < 3; ++it) {
            const int g = wv*3 + it;             // 0..11 = s*4+h
            float acc[4][6];
#pragma unroll
            for (int r=0;r<4;++r)
#pragma unroll
                for (int m=0;m<6;++m) acc[r][m] = 0.f;
            const unsigned short* wb = wsw + QKVW_OFF + (size_t)(g*24 + dg*6)*96;
            for (int k = 0; k < 96; k += 4) {
                float a4[4][4];
#pragma unroll
                for (int r=0;r<4;++r) unpack4(*(const uint2*)&hbn[tg*4+r][k], a4[r]);
#pragma unroll
                for (int m=0;m<6;++m) {
                    float w4[4];
                    unpack4(*(const uint2*)(wb + m*96 + k), w4);
#pragma unroll
                    for (int r=0;r<4;++r)
                        acc[r][m] += a4[r][0]*w4[0] + a4[r][1]*w4[1] + a4[r][2]*w4[2] + a4[r][3]*w4[3];
                }
            }
            const int s_ = g >> 2, h_ = g & 3;
            unsigned short* dstp;
            int st;
            if (s_ == 0)      { dstp = &qb[0][0][0] + h_*(NT_*26); st = 26; }
            else if (s_ == 1) { dstp = &kb[0][0][0] + h_*(NT_*24); st = 24; }
            else              { dstp = &vb[0][0][0] + h_*(NT_*24); st = 24; }
#pragma unroll
            for (int m=0;m<6;++m) {
                const float bb = qkvb[g*24 + dg*6 + m];
#pragma unroll
                for (int r=0;r<4;++r)
                    dstp[(tg*4+r)*st + dg*6+m] = f2bf(acc[r][m] + bb);
            }
        }
    }
    __syncthreads();

    // ---- P3: attention. wave = head. lane pair (l, l^32) shares token, splits keys. ----
    // BUGFIX vs round 3: loop tt covers tokens 0..31 (tt=0) and 32..63 (tt=1).
    {
        const int l = tid & 63, hd = tid >> 6;
        const int half = l >> 5;

#pragma unroll
        for (int tt = 0; tt < 2; ++tt) {
            const int tok = tt*32 + (l & 31);

            float qv[24];
            {
                const unsigned short* qrow = &qb[hd][tok][0];
#pragma unroll
                for (int d2 = 0; d2 < 12; ++d2) {
                    unsigned int u = *(const unsigned int*)&qrow[d2*2];
                    qv[2*d2]   = bf2f((unsigned short)u);
                    qv[2*d2+1] = bf2f((unsigned short)(u >> 16));
                }
            }
            const int i1 = tok >> 3, j1 = tok & 7;
            const int rg1 = ((whi==7) ? ((i1<SSZ)?1:2) : 0)*3 + ((wwi==7) ? ((j1<SSZ)?1:2) : 0);

            float s[32];
#pragma unroll
            for (int jj = 0; jj < 32; ++jj) {
                const int n2 = half*32 + jj;
                float kvv[24];
                {
                    const uint4* kr = (const uint4*)&kb[hd][n2][0];
                    unpack8(kr[0], &kvv[0]); unpack8(kr[1], &kvv[8]); unpack8(kr[2], &kvv[16]);
                }
                float acc = 0.f;
#pragma unroll
                for (int d = 0; d < 24; ++d) acc += qv[d]*kvv[d];
                const int i2 = n2 >> 3, j2 = n2 & 7;
                const int rg2 = ((whi==7) ? ((i2<SSZ)?1:2) : 0)*3 + ((wwi==7) ? ((j2<SSZ)?1:2) : 0);
                float sv = acc*0.20412414523193154f + rpbt[((i1-i2+7)*15 + (j1-j2+7))*4 + hd];
                if (rg1 != rg2) sv -= 100.f;
                s[jj] = sv;
            }
            // softmax across the (l, l^32) pair
            float mx = s[0];
#pragma unroll
            for (int jj = 1; jj < 32; ++jj) mx = fmaxf(mx, s[jj]);
            mx = fmaxf(mx, __shfl_xor(mx, 32));
            float sum = 0.f;
#pragma unroll
            for (int jj = 0; jj < 32; ++jj) { s[jj] = __expf(s[jj]-mx); sum += s[jj]; }
            sum += __shfl_xor(sum, 32);
            const float inv = 1.f / sum;

            float o[24];
#pragma unroll
            for (int d = 0; d < 24; ++d) o[d] = 0.f;
#pragma unroll
            for (int jj = 0; jj < 32; ++jj) {
                const int n2 = half*32 + jj;
                const float p = s[jj];
                float vvv[24];
                {
                    const uint4* vr = (const uint4*)&vb[hd][n2][0];
                    unpack8(vr[0], &vvv[0]); unpack8(vr[1], &vvv[8]); unpack8(vr[2], &vvv[16]);
                }
#pragma unroll
                for (int d = 0; d < 24; ++d) o[d] += p*vvv[d];
            }
#pragma unroll
            for (int d = 0; d < 24; ++d) o[d] += __shfl_xor(o[d], 32);

            if (half == 0) {
#pragma unroll
                for (int d2 = 0; d2 < 12; ++d2) {
                    unsigned int u = (unsigned int)f2bf(o[2*d2]*inv)
                                   | ((unsigned int)f2bf(o[2*d2+1]*inv) << 16);
                    *(unsigned int*)&hbn[tok][hd*24 + 2*d2] = u;   // reuse hbn as attn-out
                }
            }
        }
    }
    __syncthreads();

    // ---- P4: proj + residual + scatter through shift ----
    {
        const int cg = tid >> 4;             // col group: c = cg*6..+5
        const int ng = tid & 15;             // tokens ng*4..+3
        float acc[4][6];
#pragma unroll
        for (int r=0;r<4;++r)
#pragma unroll
            for (int m=0;m<6;++m) acc[r][m] = 0.f;
        for (int k = 0; k < 96; k += 4) {
            float a4[4][4];
#pragma unroll
            for (int r=0;r<4;++r) unpack4(*(const uint2*)&hbn[ng*4+r][k], a4[r]);
#pragma unroll
            for (int m=0;m<6;++m) {
                float w4[4];
                unpack4(*(const uint2*)(wsw + PROJW_OFF + (size_t)(cg*6+m)*96 + k), w4);
#pragma unroll
                for (int r=0;r<4;++r)
                    acc[r][m] += a4[r][0]*w4[0] + a4[r][1]*w4[1] + a4[r][2]*w4[2] + a4[r][3]*w4[3];
            }
        }
#pragma unroll
        for (int r=0;r<4;++r) {
            const int n = ng*4+r;
            const int i = n >> 3, j = n & 7;
            const int sr = (whi*WSZ + i + SSZ) & (H_-1);
            const int sc = (wwi*WSZ + j + SSZ) & (W_-1);
            const float* xr  = x    + ((size_t)b*L_ + sr*W_ + sc)*C_;
            float*      orow = xmid + ((size_t)b*L_ + sr*W_ + sc)*C_;
#pragma unroll
            for (int m=0;m<6;++m) {
                const int c = cg*6+m;
                orow[c] = acc[r][m] + projb[c] + xr[c];
            }
        }
    }
}

// ---------------- Kernel 2: LN2 + fc1 + GELU + fc2 + residual (MFMA bf16) ----------------
// block: 256 thr (4 waves), 64 rows. wave wv owns m-tile wv (16 rows).
__global__ __launch_bounds__(256, 2)
void k_mlp(float* xio,
           const float* __restrict__ g2, const float* __restrict__ b2,
           const unsigned short* __restrict__ wsw,
           const float* __restrict__ bb1, const float* __restrict__ bb2)
{
    const int r0 = blockIdx.x * 64;
    const int tid = threadIdx.x;
    const int l = tid & 63, wv = tid >> 6;

    __shared__ __align__(16) unsigned short hbn[64][120];   // LN2 out bf16 (15.4KB)
    __shared__ __align__(16) unsigned short h1s[64][392];   // gelu(fc1) bf16 (50.2KB)

    // ---- LN2 (4 threads/row) -> hbn bf16 ----
    {
        const int rr = tid >> 2, q = tid & 3;
        const float* row = xio + (size_t)(r0+rr)*C_;
        float v[24];
        float s = 0.f, s2 = 0.f;
#pragma unroll
        for (int m = 0; m < 6; ++m) {
            float4 f = ((const float4*)row)[q + 4*m];
            v[4*m+0]=f.x; v[4*m+1]=f.y; v[4*m+2]=f.z; v[4*m+3]=f.w;
            s  += f.x+f.y+f.z+f.w;
            s2 += f.x*f.x+f.y*f.y+f.z*f.z+f.w*f.w;
        }
        s  += __shfl_xor(s, 1);  s  += __shfl_xor(s, 2);
        s2 += __shfl_xor(s2, 1); s2 += __shfl_xor(s2, 2);
        const float mu = s * (1.f/96.f);
        const float rstd = rsqrtf(s2*(1.f/96.f) - mu*mu + 1e-5f);
#pragma unroll
        for (int m = 0; m < 6; ++m) {
            const int c0 = 4*(q + 4*m);
            float o0 = (v[4*m+0]-mu)*rstd*g2[c0+0] + b2[c0+0];
            float o1 = (v[4*m+1]-mu)*rstd*g2[c0+1] + b2[c0+1];
            float o2 = (v[4*m+2]-mu)*rstd*g2[c0+2] + b2[c0+2];
            float o3 = (v[4*m+3]-mu)*rstd*g2[c0+3] + b2[c0+3];
            uint2 u;
            u.x = (unsigned int)f2bf(o0) | ((unsigned int)f2bf(o1) << 16);
            u.y = (unsigned int)f2bf(o2) | ((unsigned int)f2bf(o3) << 16);
            *(uint2*)&hbn[rr][c0] = u;
        }
    }
    __syncthreads();

    // ---- fc1 (M=64,N=384,K=96) MFMA + bias + exact GELU -> h1s bf16 ----
    {
        const int lr = l & 15, lk = l >> 4;  // A row / B col | k-group
        f32x4 acc[24];
#pragma unroll
        for (int t = 0; t < 24; ++t) acc[t] = (f32x4){0.f,0.f,0.f,0.f};
#pragma unroll
        for (int ks = 0; ks < 3; ++ks) {
            bf16x8 a = *(const bf16x8*)&hbn[wv*16 + lr][ks*32 + lk*8];
#pragma unroll
            for (int nt = 0; nt < 24; ++nt) {
                bf16x8 bf = *(const bf16x8*)(wsw + W1_OFF + (size_t)(nt*16 + lr)*96 + ks*32 + lk*8);
                acc[nt] = __builtin_amdgcn_mfma_f32_16x16x32_bf16(a, bf, acc[nt], 0, 0, 0);
            }
        }
#pragma unroll
        for (int nt = 0; nt < 24; ++nt) {
            const int col = nt*16 + lr;
            const float bias = bb1[col];
#pragma unroll
            for (int i = 0; i < 4; ++i) {
                const int rrow = wv*16 + lk*4 + i;          // C/D: row=(l>>4)*4+i, col=l&15
                const float t = acc[nt][i] + bias;
                h1s[rrow][col] = f2bf(0.5f*t*(1.f + erff(t*0.70710678118654752f)));
            }
        }
    }
    __syncthreads();

    // ---- fc2 (M=64,N=96,K=384) MFMA + bias + residual -> xio ----
    {
        const int lr = l & 15, lk = l >> 4;
        f32x4 acc[6];
#pragma unroll
        for (int t = 0; t < 6; ++t) acc[t] = (f32x4){0.f,0.f,0.f,0.f};
#pragma unroll
        for (int ks = 0; ks < 12; ++ks) {
            bf16x8 a = *(const bf16x8*)&h1s[wv*16 + lr][ks*32 + lk*8];
#pragma unroll
            for (int nt = 0; nt < 6; ++nt) {
                bf16x8 bf = *(const bf16x8*)(wsw + W2_OFF + (size_t)(nt*16 + lr)*384 + ks*32 + lk*8);
                acc[nt] = __builtin_amdgcn_mfma_f32_16x16x32_bf16(a, bf, acc[nt], 0, 0, 0);
            }
        }
#pragma unroll
        for (int nt = 0; nt < 6; ++nt) {
            const int col = nt*16 + lr;
            const float bias = bb2[col];
#pragma unroll
            for (int i = 0; i < 4; ++i) {
                const int row = r0 + wv*16 + lk*4 + i;
                float* p = xio + (size_t)row*C_ + col;
                *p = acc[nt][i] + bias + *p;
            }
        }
    }
}

extern "C" void kernel_launch(void* const* d_in, const int* in_sizes, int n_in,
                              void* d_out, int out_size, void* d_ws, size_t ws_size,
                              hipStream_t stream) {
    const float* x    = (const float*)d_in[0];
    const float* n1g  = (const float*)d_in[1];
    const float* n1b  = (const float*)d_in[2];
    const float* qkvw = (const float*)d_in[3];
    const float* qkvb = (const float*)d_in[4];
    const float* rpbt = (const float*)d_in[5];
    const float* pw   = (const float*)d_in[6];
    const float* pb   = (const float*)d_in[7];
    const float* n2g  = (const float*)d_in[8];
    const float* n2b  = (const float*)d_in[9];
    const float* w1   = (const float*)d_in[10];
    const float* b1f  = (const float*)d_in[11];
    const float* w2   = (const float*)d_in[12];
    const float* b2f  = (const float*)d_in[13];
    float* outp = (float*)d_out;
    unsigned short* wsw = (unsigned short*)d_ws;

    k_conv<<<dim3((WTOT + 255)/256), dim3(256), 0, stream>>>(qkvw, pw, w1, w2, wsw);
    k_attn<<<dim3(4096), dim3(256), 0, stream>>>(x, n1g, n1b, wsw, qkvb, rpbt, pb, outp);
    k_mlp <<<dim3(4096), dim3(256), 0, stream>>>(outp, n2g, n2b, wsw, b1f, b2f);
}

// Round 5
// 903.588 us; speedup vs baseline: 2.6281x; 2.6281x over previous
//
#include <hip/hip_runtime.h>
#include <math.h>

#define B_IMG 64
#define H_ 64
#define W_ 64
#define L_ (H_*W_)
#define C_ 96
#define WSZ 8
#define SSZ 4
#define NH_ 4
#define HD_ 24
#define NT_ 64

// bf16 weight workspace layout (element offsets, 2B each)
#define QKVW_OFF 0
#define PROJW_OFF 27648     // 288*96
#define W1_OFF   36864      // +96*96
#define W2_OFF   73728      // +384*96
#define WTOT     110592     // +96*384

typedef short bf16x8 __attribute__((ext_vector_type(8)));
typedef float f32x4  __attribute__((ext_vector_type(4)));

__device__ __forceinline__ float bf2f(unsigned short u) {
    union { unsigned int i; float f; } c; c.i = ((unsigned int)u) << 16; return c.f;
}
__device__ __forceinline__ unsigned short f2bf(float f) {
    union { float f; unsigned int i; } c; c.f = f;
    return (unsigned short)((c.i + 0x7fffu + ((c.i >> 16) & 1u)) >> 16);  // RNE
}

// ---------------- Kernel 0: convert weights fp32 -> bf16 into d_ws ----------------
__global__ void k_conv(const float* __restrict__ qkvw, const float* __restrict__ projw,
                       const float* __restrict__ w1, const float* __restrict__ w2,
                       unsigned short* __restrict__ ws16) {
    int i = blockIdx.x * 256 + threadIdx.x;
    if (i >= WTOT) return;
    float v;
    if (i < PROJW_OFF)      v = qkvw[i];
    else if (i < W1_OFF)    v = projw[i - PROJW_OFF];
    else if (i < W2_OFF)    v = w1[i - W1_OFF];
    else                    v = w2[i - W2_OFF];
    ws16[i] = f2bf(v);
}

// ---------------- Kernel 1: LN1 + shifted-window attention + proj + residual ----------------
// one block per window. P2/P4 use MFMA (pattern validated by k_mlp in round 4).
// LDS 76 KB -> 2 blocks/CU. NO second launch_bounds arg (round-4: it caused VGPR=84 + 3GB spill).
__global__ __launch_bounds__(256)
void k_attn(const float* __restrict__ x,
            const float* __restrict__ g1, const float* __restrict__ b1,
            const unsigned short* __restrict__ wsw,
            const float* __restrict__ qkvb,
            const float* __restrict__ rpbt,
            const float* __restrict__ projb,
            float* __restrict__ xmid)
{
    const int wid = blockIdx.x;
    const int b = wid >> 6, whi = (wid >> 3) & 7, wwi = wid & 7;
    const int tid = threadIdx.x;
    const int l = tid & 63, wv = tid >> 6;
    const int lr = l & 15, lk = l >> 4;

    __shared__ __align__(16) unsigned short hbn[NT_][120];  // LN out bf16; later attn-out (15.4KB)
    __shared__ __align__(16) unsigned short qb[NH_][NT_][26]; // q bf16, 13-dw rows (conflict-free) 13.3KB
    __shared__ __align__(16) float kbf[NH_][NT_][24];       // k f32 (24.6KB)
    __shared__ __align__(16) float vbf[NH_][NT_][24];       // v f32 (24.6KB)

    // ---- P1: LayerNorm -> hbn (bf16) ----
    {
        const int tok = tid >> 2, q = tid & 3;
        const int i = tok >> 3, j = tok & 7;
        const int sr = (whi*WSZ + i + SSZ) & (H_-1);
        const int sc = (wwi*WSZ + j + SSZ) & (W_-1);
        const float* row = x + ((size_t)b*L_ + sr*W_ + sc) * C_;
        float v[24];
        float s = 0.f, s2 = 0.f;
#pragma unroll
        for (int m = 0; m < 6; ++m) {
            float4 f = ((const float4*)row)[q + 4*m];
            v[4*m+0]=f.x; v[4*m+1]=f.y; v[4*m+2]=f.z; v[4*m+3]=f.w;
            s  += f.x+f.y+f.z+f.w;
            s2 += f.x*f.x+f.y*f.y+f.z*f.z+f.w*f.w;
        }
        s  += __shfl_xor(s, 1);  s  += __shfl_xor(s, 2);
        s2 += __shfl_xor(s2, 1); s2 += __shfl_xor(s2, 2);
        const float mu = s * (1.f/96.f);
        const float rstd = rsqrtf(s2*(1.f/96.f) - mu*mu + 1e-5f);
#pragma unroll
        for (int m = 0; m < 6; ++m) {
            const int c0 = 4*(q + 4*m);
            float o0 = (v[4*m+0]-mu)*rstd*g1[c0+0] + b1[c0+0];
            float o1 = (v[4*m+1]-mu)*rstd*g1[c0+1] + b1[c0+1];
            float o2 = (v[4*m+2]-mu)*rstd*g1[c0+2] + b1[c0+2];
            float o3 = (v[4*m+3]-mu)*rstd*g1[c0+3] + b1[c0+3];
            uint2 u;
            u.x = (unsigned int)f2bf(o0) | ((unsigned int)f2bf(o1) << 16);
            u.y = (unsigned int)f2bf(o2) | ((unsigned int)f2bf(o3) << 16);
            *(uint2*)&hbn[tok][c0] = u;
        }
    }
    __syncthreads();

    // ---- P2: QKV GEMM via MFMA (M=64, N=288, K=96). wave wv = M-tile wv. ----
    {
        f32x4 acc[18];
#pragma unroll
        for (int nt = 0; nt < 18; ++nt) acc[nt] = (f32x4){0.f,0.f,0.f,0.f};
#pragma unroll
        for (int ks = 0; ks < 3; ++ks) {
            bf16x8 a = *(const bf16x8*)&hbn[wv*16 + lr][ks*32 + lk*8];
#pragma unroll
            for (int nt = 0; nt < 18; ++nt) {
                bf16x8 bw = *(const bf16x8*)(wsw + QKVW_OFF + (size_t)(nt*16 + lr)*96 + ks*32 + lk*8);
                acc[nt] = __builtin_amdgcn_mfma_f32_16x16x32_bf16(a, bw, acc[nt], 0, 0, 0);
            }
        }
        // scatter: col = nt*16+lr -> seg(q/k/v) = nt/6 (compile-time), head = cs/24, d = cs%24
#pragma unroll
        for (int nt = 0; nt < 18; ++nt) {
            const int col = nt*16 + lr;
            const int seg = nt / 6;                  // 0:q 1:k 2:v (nt static)
            const int cs  = col - seg*96;            // 0..95
            const int hh  = cs / 24;                 // head
            const int dd  = cs - hh*24;              // dim
            const float bias = qkvb[col];
#pragma unroll
            for (int i = 0; i < 4; ++i) {
                const int row = wv*16 + lk*4 + i;    // C/D: row=(l>>4)*4+i, col=l&15
                const float val = acc[nt][i] + bias;
                if (seg == 0)      qb[hh][row][dd]  = f2bf(val);
                else if (seg == 1) kbf[hh][row][dd] = val;
                else               vbf[hh][row][dd] = val;
            }
        }
    }
    __syncthreads();

    // ---- P3: attention (scalar). wave = head. lane pair (l, l^32) shares token, splits keys. ----
    {
        const int hd = wv;
        const int half = l >> 5;

#pragma unroll
        for (int tt = 0; tt < 2; ++tt) {
            const int tok = tt*32 + (l & 31);

            float qv[24];
#pragma unroll
            for (int d2 = 0; d2 < 12; ++d2) {
                unsigned int u = *(const unsigned int*)&qb[hd][tok][2*d2];
                qv[2*d2]   = bf2f((unsigned short)u);
                qv[2*d2+1] = bf2f((unsigned short)(u >> 16));
            }
            const int i1 = tok >> 3, j1 = tok & 7;
            const int rg1 = ((whi==7) ? ((i1<SSZ)?1:2) : 0)*3 + ((wwi==7) ? ((j1<SSZ)?1:2) : 0);

            float s[32];
#pragma unroll
            for (int jj = 0; jj < 32; ++jj) {
                const int n2 = half*32 + jj;
                const float4* kr = (const float4*)&kbf[hd][n2][0];
                const float4 k0 = kr[0], k1 = kr[1], k2 = kr[2], k3 = kr[3], k4 = kr[4], k5 = kr[5];
                float acc;
                acc  = qv[0]*k0.x + qv[1]*k0.y + qv[2]*k0.z + qv[3]*k0.w;
                acc += qv[4]*k1.x + qv[5]*k1.y + qv[6]*k1.z + qv[7]*k1.w;
                acc += qv[8]*k2.x + qv[9]*k2.y + qv[10]*k2.z + qv[11]*k2.w;
                acc += qv[12]*k3.x + qv[13]*k3.y + qv[14]*k3.z + qv[15]*k3.w;
                acc += qv[16]*k4.x + qv[17]*k4.y + qv[18]*k4.z + qv[19]*k4.w;
                acc += qv[20]*k5.x + qv[21]*k5.y + qv[22]*k5.z + qv[23]*k5.w;
                const int i2 = n2 >> 3, j2 = n2 & 7;
                const int rg2 = ((whi==7) ? ((i2<SSZ)?1:2) : 0)*3 + ((wwi==7) ? ((j2<SSZ)?1:2) : 0);
                float sv = acc*0.20412414523193154f + rpbt[((i1-i2+7)*15 + (j1-j2+7))*4 + hd];
                if (rg1 != rg2) sv -= 100.f;
                s[jj] = sv;
            }
            float mx = s[0];
#pragma unroll
            for (int jj = 1; jj < 32; ++jj) mx = fmaxf(mx, s[jj]);
            mx = fmaxf(mx, __shfl_xor(mx, 32));
            float sum = 0.f;
#pragma unroll
            for (int jj = 0; jj < 32; ++jj) { s[jj] = __expf(s[jj]-mx); sum += s[jj]; }
            sum += __shfl_xor(sum, 32);
            const float inv = 1.f / sum;

            float o[24];
#pragma unroll
            for (int d = 0; d < 24; ++d) o[d] = 0.f;
#pragma unroll
            for (int jj = 0; jj < 32; ++jj) {
                const int n2 = half*32 + jj;
                const float p = s[jj];
                const float4* vr = (const float4*)&vbf[hd][n2][0];
                const float4 v0 = vr[0], v1 = vr[1], v2 = vr[2], v3 = vr[3], v4 = vr[4], v5 = vr[5];
                o[0] += p*v0.x;  o[1] += p*v0.y;  o[2] += p*v0.z;  o[3] += p*v0.w;
                o[4] += p*v1.x;  o[5] += p*v1.y;  o[6] += p*v1.z;  o[7] += p*v1.w;
                o[8] += p*v2.x;  o[9] += p*v2.y;  o[10]+= p*v2.z;  o[11]+= p*v2.w;
                o[12]+= p*v3.x;  o[13]+= p*v3.y;  o[14]+= p*v3.z;  o[15]+= p*v3.w;
                o[16]+= p*v4.x;  o[17]+= p*v4.y;  o[18]+= p*v4.z;  o[19]+= p*v4.w;
                o[20]+= p*v5.x;  o[21]+= p*v5.y;  o[22]+= p*v5.z;  o[23]+= p*v5.w;
            }
#pragma unroll
            for (int d = 0; d < 24; ++d) o[d] += __shfl_xor(o[d], 32);

            if (half == 0) {
#pragma unroll
                for (int d2 = 0; d2 < 12; ++d2) {
                    unsigned int u = (unsigned int)f2bf(o[2*d2]*inv)
                                   | ((unsigned int)f2bf(o[2*d2+1]*inv) << 16);
                    *(unsigned int*)&hbn[tok][hd*24 + 2*d2] = u;   // attn-out into hbn cols 0..95
                }
            }
        }
    }
    __syncthreads();

    // ---- P4: proj via MFMA (M=64, N=96, K=96) + bias + residual + shifted scatter ----
    {
        f32x4 pacc[6];
#pragma unroll
        for (int nt = 0; nt < 6; ++nt) pacc[nt] = (f32x4){0.f,0.f,0.f,0.f};
#pragma unroll
        for (int ks = 0; ks < 3; ++ks) {
            bf16x8 a = *(const bf16x8*)&hbn[wv*16 + lr][ks*32 + lk*8];
#pragma unroll
            for (int nt = 0; nt < 6; ++nt) {
                bf16x8 bw = *(const bf16x8*)(wsw + PROJW_OFF + (size_t)(nt*16 + lr)*96 + ks*32 + lk*8);
                pacc[nt] = __builtin_amdgcn_mfma_f32_16x16x32_bf16(a, bw, pacc[nt], 0, 0, 0);
            }
        }
#pragma unroll
        for (int i = 0; i < 4; ++i) {
            const int n = wv*16 + lk*4 + i;          // window token
            const int wi = n >> 3, wj = n & 7;
            const int sr = (whi*WSZ + wi + SSZ) & (H_-1);
            const int sc = (wwi*WSZ + wj + SSZ) & (W_-1);
            const size_t base = ((size_t)b*L_ + sr*W_ + sc)*C_;
#pragma unroll
            for (int nt = 0; nt < 6; ++nt) {
                const int c = nt*16 + lr;
                xmid[base + c] = pacc[nt][i] + projb[c] + x[base + c];
            }
        }
    }
}

// ---------------- Kernel 2: LN2 + fc1 + GELU + fc2 + residual (MFMA bf16) ----------------
__global__ __launch_bounds__(256)
void k_mlp(float* xio,
           const float* __restrict__ g2, const float* __restrict__ b2,
           const unsigned short* __restrict__ wsw,
           const float* __restrict__ bb1, const float* __restrict__ bb2)
{
    const int r0 = blockIdx.x * 64;
    const int tid = threadIdx.x;
    const int l = tid & 63, wv = tid >> 6;

    __shared__ __align__(16) unsigned short hbn[64][120];   // LN2 out bf16 (15.4KB)
    __shared__ __align__(16) unsigned short h1s[64][392];   // gelu(fc1) bf16 (50.2KB)

    // ---- LN2 (4 threads/row) -> hbn bf16 ----
    {
        const int rr = tid >> 2, q = tid & 3;
        const float* row = xio + (size_t)(r0+rr)*C_;
        float v[24];
        float s = 0.f, s2 = 0.f;
#pragma unroll
        for (int m = 0; m < 6; ++m) {
            float4 f = ((const float4*)row)[q + 4*m];
            v[4*m+0]=f.x; v[4*m+1]=f.y; v[4*m+2]=f.z; v[4*m+3]=f.w;
            s  += f.x+f.y+f.z+f.w;
            s2 += f.x*f.x+f.y*f.y+f.z*f.z+f.w*f.w;
        }
        s  += __shfl_xor(s, 1);  s  += __shfl_xor(s, 2);
        s2 += __shfl_xor(s2, 1); s2 += __shfl_xor(s2, 2);
        const float mu = s * (1.f/96.f);
        const float rstd = rsqrtf(s2*(1.f/96.f) - mu*mu + 1e-5f);
#pragma unroll
        for (int m = 0; m < 6; ++m) {
            const int c0 = 4*(q + 4*m);
            float o0 = (v[4*m+0]-mu)*rstd*g2[c0+0] + b2[c0+0];
            float o1 = (v[4*m+1]-mu)*rstd*g2[c0+1] + b2[c0+1];
            float o2 = (v[4*m+2]-mu)*rstd*g2[c0+2] + b2[c0+2];
            float o3 = (v[4*m+3]-mu)*rstd*g2[c0+3] + b2[c0+3];
            uint2 u;
            u.x = (unsigned int)f2bf(o0) | ((unsigned int)f2bf(o1) << 16);
            u.y = (unsigned int)f2bf(o2) | ((unsigned int)f2bf(o3) << 16);
            *(uint2*)&hbn[rr][c0] = u;
        }
    }
    __syncthreads();

    // ---- fc1 (M=64,N=384,K=96) MFMA + bias + exact GELU -> h1s bf16 ----
    {
        const int lr = l & 15, lk = l >> 4;
        f32x4 acc[24];
#pragma unroll
        for (int t = 0; t < 24; ++t) acc[t] = (f32x4){0.f,0.f,0.f,0.f};
#pragma unroll
        for (int ks = 0; ks < 3; ++ks) {
            bf16x8 a = *(const bf16x8*)&hbn[wv*16 + lr][ks*32 + lk*8];
#pragma unroll
            for (int nt = 0; nt < 24; ++nt) {
                bf16x8 bf = *(const bf16x8*)(wsw + W1_OFF + (size_t)(nt*16 + lr)*96 + ks*32 + lk*8);
                acc[nt] = __builtin_amdgcn_mfma_f32_16x16x32_bf16(a, bf, acc[nt], 0, 0, 0);
            }
        }
#pragma unroll
        for (int nt = 0; nt < 24; ++nt) {
            const int col = nt*16 + lr;
            const float bias = bb1[col];
#pragma unroll
            for (int i = 0; i < 4; ++i) {
                const int rrow = wv*16 + lk*4 + i;
                const float t = acc[nt][i] + bias;
                h1s[rrow][col] = f2bf(0.5f*t*(1.f + erff(t*0.70710678118654752f)));
            }
        }
    }
    __syncthreads();

    // ---- fc2 (M=64,N=96,K=384) MFMA + bias + residual -> xio ----
    {
        const int lr = l & 15, lk = l >> 4;
        f32x4 acc[6];
#pragma unroll
        for (int t = 0; t < 6; ++t) acc[t] = (f32x4){0.f,0.f,0.f,0.f};
#pragma unroll
        for (int ks = 0; ks < 12; ++ks) {
            bf16x8 a = *(const bf16x8*)&h1s[wv*16 + lr][ks*32 + lk*8];
#pragma unroll
            for (int nt = 0; nt < 6; ++nt) {
                bf16x8 bf = *(const bf16x8*)(wsw + W2_OFF + (size_t)(nt*16 + lr)*384 + ks*32 + lk*8);
                acc[nt] = __builtin_amdgcn_mfma_f32_16x16x32_bf16(a, bf, acc[nt], 0, 0, 0);
            }
        }
#pragma unroll
        for (int nt = 0; nt < 6; ++nt) {
            const int col = nt*16 + lr;
            const float bias = bb2[col];
#pragma unroll
            for (int i = 0; i < 4; ++i) {
                const int row = r0 + wv*16 + lk*4 + i;
                float* p = xio + (size_t)row*C_ + col;
                *p = acc[nt][i] + bias + *p;
            }
        }
    }
}

extern "C" void kernel_launch(void* const* d_in, const int* in_sizes, int n_in,
                              void* d_out, int out_size, void* d_ws, size_t ws_size,
                              hipStream_t stream) {
    const float* x    = (const float*)d_in[0];
    const float* n1g  = (const float*)d_in[1];
    const float* n1b  = (const float*)d_in[2];
    const float* qkvw = (const float*)d_in[3];
    const float* qkvb = (const float*)d_in[4];
    const float* rpbt = (const float*)d_in[5];
    const float* pw   = (const float*)d_in[6];
    const float* pb   = (const float*)d_in[7];
    const float* n2g  = (const float*)d_in[8];
    const float* n2b  = (const float*)d_in[9];
    const float* w1   = (const float*)d_in[10];
    const float* b1f  = (const float*)d_in[11];
    const float* w2   = (const float*)d_in[12];
    const float* b2f  = (const float*)d_in[13];
    float* outp = (float*)d_out;
    unsigned short* wsw = (unsigned short*)d_ws;

    k_conv<<<dim3((WTOT + 255)/256), dim3(256), 0, stream>>>(qkvw, pw, w1, w2, wsw);
    k_attn<<<dim3(4096), dim3(256), 0, stream>>>(x, n1g, n1b, wsw, qkvb, rpbt, pb, outp);
    k_mlp <<<dim3(4096), dim3(256), 0, stream>>>(outp, n2g, n2b, wsw, b1f, b2f);
}

// Round 6
// 606.868 us; speedup vs baseline: 3.9131x; 1.4889x over previous
//
#include <hip/hip_runtime.h>
#include <math.h>

#define B_IMG 64
#define H_ 64
#define W_ 64
#define L_ (H_*W_)
#define C_ 96
#define WSZ 8
#define SSZ 4
#define NH_ 4
#define HD_ 24
#define NT_ 64

// bf16 weight workspace layout (element offsets, 2B each)
#define QKVW_OFF 0
#define PROJW_OFF 27648     // 288*96
#define W1_OFF   36864      // +96*96
#define W2_OFF   73728      // +384*96
#define WTOT     110592     // +96*384

typedef short bf16x8 __attribute__((ext_vector_type(8)));
typedef float f32x4  __attribute__((ext_vector_type(4)));

__device__ __forceinline__ float bf2f(unsigned short u) {
    union { unsigned int i; float f; } c; c.i = ((unsigned int)u) << 16; return c.f;
}
__device__ __forceinline__ unsigned short f2bf(float f) {
    union { float f; unsigned int i; } c; c.f = f;
    return (unsigned short)((c.i + 0x7fffu + ((c.i >> 16) & 1u)) >> 16);  // RNE
}
__device__ __forceinline__ int reg_of(int ii, int jj, int whi, int wwi) {
    const int rh = (whi == 7) ? ((ii < SSZ) ? 1 : 2) : 0;
    const int rw = (wwi == 7) ? ((jj < SSZ) ? 1 : 2) : 0;
    return rh*3 + rw;
}

// ---------------- Kernel 0: convert weights fp32 -> bf16 into d_ws ----------------
__global__ void k_conv(const float* __restrict__ qkvw, const float* __restrict__ projw,
                       const float* __restrict__ w1, const float* __restrict__ w2,
                       unsigned short* __restrict__ ws16) {
    int i = blockIdx.x * 256 + threadIdx.x;
    if (i >= WTOT) return;
    float v;
    if (i < PROJW_OFF)      v = qkvw[i];
    else if (i < W1_OFF)    v = projw[i - PROJW_OFF];
    else if (i < W2_OFF)    v = w1[i - W1_OFF];
    else                    v = w2[i - W2_OFF];
    ws16[i] = f2bf(v);
}

// ---------------- Kernel 1: LN1 + shifted-window attention (full MFMA) + proj + residual ----------------
// one block per window; wave = head in P3. LDS ~66KB -> 2 blocks/CU.
// ps (P matrix) overlays the dead Q/K region of qkps per head (same __shared__ object -> alias-ordered).
__global__ __launch_bounds__(256)
void k_attn(const float* __restrict__ x,
            const float* __restrict__ g1, const float* __restrict__ b1,
            const unsigned short* __restrict__ wsw,
            const float* __restrict__ qkvb,
            const float* __restrict__ rpbt,
            const float* __restrict__ projb,
            float* __restrict__ xmid)
{
    const int wid = blockIdx.x;
    const int b = wid >> 6, whi = (wid >> 3) & 7, wwi = wid & 7;
    const int tid = threadIdx.x;
    const int l = tid & 63, wv = tid >> 6;
    const int e = l & 15, g = l >> 4;       // MFMA lane coords: row/col = e, k-group = g

    __shared__ __align__(16) unsigned short hbn[NT_][104];  // LN-out bf16; later attn-out (13.3KB)
    __shared__ __align__(16) unsigned short qkps[NH_][4096];// per head: Q[64][32] | K[64][32]; later P[64][64] swz (32KB)
    __shared__ __align__(16) unsigned short vt[NH_][2048];  // V^T [32][64] bf16, XOR-swizzled rows (16KB)
    __shared__ float rpbf[900];                             // rel-pos bias table (3.6KB)

    // ---- P0: zero qkps (K=32 MFMA needs k=24..31 == 0) + stage rpb ----
    {
        uint4* z = (uint4*)&qkps[0][0];
        for (int i = tid; i < 2048; i += 256) z[i] = (uint4){0,0,0,0};
        for (int i = tid; i < 900; i += 256) rpbf[i] = rpbt[i];
    }

    // ---- P1: LayerNorm -> hbn (bf16) ----
    {
        const int tok = tid >> 2, q = tid & 3;
        const int i = tok >> 3, j = tok & 7;
        const int sr = (whi*WSZ + i + SSZ) & (H_-1);
        const int sc = (wwi*WSZ + j + SSZ) & (W_-1);
        const float* row = x + ((size_t)b*L_ + sr*W_ + sc) * C_;
        float v[24];
        float s = 0.f, s2 = 0.f;
#pragma unroll
        for (int m = 0; m < 6; ++m) {
            float4 f = ((const float4*)row)[q + 4*m];
            v[4*m+0]=f.x; v[4*m+1]=f.y; v[4*m+2]=f.z; v[4*m+3]=f.w;
            s  += f.x+f.y+f.z+f.w;
            s2 += f.x*f.x+f.y*f.y+f.z*f.z+f.w*f.w;
        }
        s  += __shfl_xor(s, 1);  s  += __shfl_xor(s, 2);
        s2 += __shfl_xor(s2, 1); s2 += __shfl_xor(s2, 2);
        const float mu = s * (1.f/96.f);
        const float rstd = rsqrtf(s2*(1.f/96.f) - mu*mu + 1e-5f);
#pragma unroll
        for (int m = 0; m < 6; ++m) {
            const int c0 = 4*(q + 4*m);
            float o0 = (v[4*m+0]-mu)*rstd*g1[c0+0] + b1[c0+0];
            float o1 = (v[4*m+1]-mu)*rstd*g1[c0+1] + b1[c0+1];
            float o2 = (v[4*m+2]-mu)*rstd*g1[c0+2] + b1[c0+2];
            float o3 = (v[4*m+3]-mu)*rstd*g1[c0+3] + b1[c0+3];
            uint2 u;
            u.x = (unsigned int)f2bf(o0) | ((unsigned int)f2bf(o1) << 16);
            u.y = (unsigned int)f2bf(o2) | ((unsigned int)f2bf(o3) << 16);
            *(uint2*)&hbn[tok][c0] = u;
        }
    }
    __syncthreads();

    // ---- P2: QKV GEMM via MFMA (M=64, N=288, K=96); scatter q->Q (scaled), k->K, v->V^T(swz) ----
    {
        f32x4 acc[18];
#pragma unroll
        for (int nt = 0; nt < 18; ++nt) acc[nt] = (f32x4){0.f,0.f,0.f,0.f};
#pragma unroll
        for (int ks = 0; ks < 3; ++ks) {
            bf16x8 a = *(const bf16x8*)&hbn[wv*16 + e][ks*32 + g*8];
#pragma unroll
            for (int nt = 0; nt < 18; ++nt) {
                bf16x8 bw = *(const bf16x8*)(wsw + QKVW_OFF + (size_t)(nt*16 + e)*96 + ks*32 + g*8);
                acc[nt] = __builtin_amdgcn_mfma_f32_16x16x32_bf16(a, bw, acc[nt], 0, 0, 0);
            }
        }
#pragma unroll
        for (int nt = 0; nt < 18; ++nt) {
            const int col = nt*16 + e;
            const int seg = nt / 6;                  // 0:q 1:k 2:v (compile-time)
            const int cs  = col - seg*96;            // 0..95
            const int hh  = cs / 24;                 // head
            const int dd  = cs - hh*24;              // dim 0..23
            const float bias = qkvb[col];
#pragma unroll
            for (int i = 0; i < 4; ++i) {
                const int row = wv*16 + g*4 + i;     // token (C/D: row=(l>>4)*4+i, col=l&15)
                const float val = acc[nt][i] + bias;
                if (seg == 0)      qkps[hh][row*32 + dd] = f2bf(val * 0.20412414523193154f);
                else if (seg == 1) qkps[hh][2048 + row*32 + dd] = f2bf(val);
                else               vt[hh][dd*64 + ((((row*2) ^ ((dd&7)<<4))) >> 1)] = f2bf(val);
            }
        }
    }
    __syncthreads();

    // ---- P3: attention via MFMA. wave = head. ----
    {
        const int hd = wv;
        const unsigned short* qbase = &qkps[hd][0];
        const unsigned short* kbase = &qkps[hd][2048];
        unsigned short* psb = &qkps[hd][0];          // P overlays Q|K after QK^T done (this wave only)

        // QK^T: S[64][64], K-dim 32 (24 + zero pad)
        f32x4 acc[4][4];
        {
            bf16x8 qf[4], kf[4];
#pragma unroll
            for (int mt = 0; mt < 4; ++mt)
                qf[mt] = *(const bf16x8*)(qbase + (mt*16 + e)*32 + g*8);
#pragma unroll
            for (int nt = 0; nt < 4; ++nt)
                kf[nt] = *(const bf16x8*)(kbase + (nt*16 + e)*32 + g*8);
            const f32x4 zz = (f32x4){0.f,0.f,0.f,0.f};
#pragma unroll
            for (int mt = 0; mt < 4; ++mt)
#pragma unroll
                for (int nt = 0; nt < 4; ++nt)
                    acc[mt][nt] = __builtin_amdgcn_mfma_f32_16x16x32_bf16(qf[mt], kf[nt], zz, 0, 0, 0);
        }

        // bias + mask + row softmax (rows live across 16 lanes sharing g) + pack bf16 -> ps (swizzled)
        const int j2 = e & 7, i2b = e >> 3;          // col c = nt*16+e -> (i2 = nt*2+i2b, j2)
        int rgc[4];
#pragma unroll
        for (int nt = 0; nt < 4; ++nt) rgc[nt] = reg_of(nt*2 + i2b, j2, whi, wwi);

#pragma unroll
        for (int mt = 0; mt < 4; ++mt) {
#pragma unroll
            for (int ii = 0; ii < 4; ++ii) {
                const int r  = mt*16 + g*4 + ii;     // query token
                const int i1 = r >> 3, j1 = r & 7;
                const int rg1 = reg_of(i1, j1, whi, wwi);
                const int cbase = ((i1 + 7 - i2b)*15 + (j1 - j2 + 7))*4 + hd;  // idx = cbase - nt*120
                float sv[4];
#pragma unroll
                for (int nt = 0; nt < 4; ++nt) {
                    float t = acc[mt][nt][ii] + rpbf[cbase - nt*120];
                    if (rg1 != rgc[nt]) t -= 100.f;
                    sv[nt] = t;
                }
                float m = fmaxf(fmaxf(sv[0], sv[1]), fmaxf(sv[2], sv[3]));
                m = fmaxf(m, __shfl_xor(m, 1)); m = fmaxf(m, __shfl_xor(m, 2));
                m = fmaxf(m, __shfl_xor(m, 4)); m = fmaxf(m, __shfl_xor(m, 8));
                float sum = 0.f;
#pragma unroll
                for (int nt = 0; nt < 4; ++nt) { sv[nt] = __expf(sv[nt] - m); sum += sv[nt]; }
                sum += __shfl_xor(sum, 1); sum += __shfl_xor(sum, 2);
                sum += __shfl_xor(sum, 4); sum += __shfl_xor(sum, 8);
                const float inv = 1.f / sum;
                const int swx = (r & 7) << 4;
#pragma unroll
                for (int nt = 0; nt < 4; ++nt) {
                    const int cbyte = (nt*16 + e)*2;
                    psb[r*64 + ((cbyte ^ swx) >> 1)] = f2bf(sv[nt] * inv);
                }
            }
        }
        // drain LDS writes before cross-lane reads of ps (insurance; same wave, cross-lane)
        asm volatile("s_waitcnt lgkmcnt(0)" ::: "memory");

        // PV: O[64][24] = P[64][64] @ V ; B = V^T[32][64] (swizzled), K-dim 64 in 2 steps
        f32x4 acc2[4][2];
#pragma unroll
        for (int mt = 0; mt < 4; ++mt)
#pragma unroll
            for (int nt2 = 0; nt2 < 2; ++nt2) acc2[mt][nt2] = (f32x4){0.f,0.f,0.f,0.f};
#pragma unroll
        for (int ks2 = 0; ks2 < 2; ++ks2) {
            bf16x8 pf[4], vf[2];
#pragma unroll
            for (int mt = 0; mt < 4; ++mt) {
                const int rr = mt*16 + e;
                const int gg = (ks2*4 + g) ^ (rr & 7);
                pf[mt] = *(const bf16x8*)(psb + rr*64 + gg*8);
            }
#pragma unroll
            for (int nt2 = 0; nt2 < 2; ++nt2) {
                const int d = nt2*16 + e;
                const int gg = (ks2*4 + g) ^ (d & 7);
                vf[nt2] = *(const bf16x8*)(&vt[hd][0] + d*64 + gg*8);
            }
#pragma unroll
            for (int mt = 0; mt < 4; ++mt)
#pragma unroll
                for (int nt2 = 0; nt2 < 2; ++nt2)
                    acc2[mt][nt2] = __builtin_amdgcn_mfma_f32_16x16x32_bf16(pf[mt], vf[nt2], acc2[mt][nt2], 0, 0, 0);
        }
        // O -> hbn cols hd*24..+23 (d = nt2*16+e, valid d<24)
#pragma unroll
        for (int mt = 0; mt < 4; ++mt) {
#pragma unroll
            for (int ii = 0; ii < 4; ++ii) {
                const int r = mt*16 + g*4 + ii;
                hbn[r][hd*24 + e] = f2bf(acc2[mt][0][ii]);
                if (e < 8) hbn[r][hd*24 + 16 + e] = f2bf(acc2[mt][1][ii]);
            }
        }
    }
    __syncthreads();

    // ---- P4: proj via MFMA (M=64, N=96, K=96) + bias + residual + shifted scatter ----
    {
        f32x4 pacc[6];
#pragma unroll
        for (int nt = 0; nt < 6; ++nt) pacc[nt] = (f32x4){0.f,0.f,0.f,0.f};
#pragma unroll
        for (int ks = 0; ks < 3; ++ks) {
            bf16x8 a = *(const bf16x8*)&hbn[wv*16 + e][ks*32 + g*8];
#pragma unroll
            for (int nt = 0; nt < 6; ++nt) {
                bf16x8 bw = *(const bf16x8*)(wsw + PROJW_OFF + (size_t)(nt*16 + e)*96 + ks*32 + g*8);
                pacc[nt] = __builtin_amdgcn_mfma_f32_16x16x32_bf16(a, bw, pacc[nt], 0, 0, 0);
            }
        }
#pragma unroll
        for (int i = 0; i < 4; ++i) {
            const int n = wv*16 + g*4 + i;           // window token
            const int wi = n >> 3, wj = n & 7;
            const int sr = (whi*WSZ + wi + SSZ) & (H_-1);
            const int sc = (wwi*WSZ + wj + SSZ) & (W_-1);
            const size_t base = ((size_t)b*L_ + sr*W_ + sc)*C_;
#pragma unroll
            for (int nt = 0; nt < 6; ++nt) {
                const int c = nt*16 + e;
                xmid[base + c] = pacc[nt][i] + projb[c] + x[base + c];
            }
        }
    }
}

// ---------------- Kernel 2: LN2 + fc1 + GELU + fc2 + residual (MFMA bf16) ----------------
// fc1 split into two N-halves (acc[12] = 48 VGPR) to keep register pressure low.
__global__ __launch_bounds__(256)
void k_mlp(float* xio,
           const float* __restrict__ g2, const float* __restrict__ b2,
           const unsigned short* __restrict__ wsw,
           const float* __restrict__ bb1, const float* __restrict__ bb2)
{
    const int r0 = blockIdx.x * 64;
    const int tid = threadIdx.x;
    const int l = tid & 63, wv = tid >> 6;
    const int lr = l & 15, lk = l >> 4;

    __shared__ __align__(16) unsigned short hbn[64][120];   // LN2 out bf16 (15.4KB)
    __shared__ __align__(16) unsigned short h1s[64][392];   // gelu(fc1) bf16 (50.2KB)

    // ---- LN2 (4 threads/row) -> hbn bf16 ----
    {
        const int rr = tid >> 2, q = tid & 3;
        const float* row = xio + (size_t)(r0+rr)*C_;
        float v[24];
        float s = 0.f, s2 = 0.f;
#pragma unroll
        for (int m = 0; m < 6; ++m) {
            float4 f = ((const float4*)row)[q + 4*m];
            v[4*m+0]=f.x; v[4*m+1]=f.y; v[4*m+2]=f.z; v[4*m+3]=f.w;
            s  += f.x+f.y+f.z+f.w;
            s2 += f.x*f.x+f.y*f.y+f.z*f.z+f.w*f.w;
        }
        s  += __shfl_xor(s, 1);  s  += __shfl_xor(s, 2);
        s2 += __shfl_xor(s2, 1); s2 += __shfl_xor(s2, 2);
        const float mu = s * (1.f/96.f);
        const float rstd = rsqrtf(s2*(1.f/96.f) - mu*mu + 1e-5f);
#pragma unroll
        for (int m = 0; m < 6; ++m) {
            const int c0 = 4*(q + 4*m);
            float o0 = (v[4*m+0]-mu)*rstd*g2[c0+0] + b2[c0+0];
            float o1 = (v[4*m+1]-mu)*rstd*g2[c0+1] + b2[c0+1];
            float o2 = (v[4*m+2]-mu)*rstd*g2[c0+2] + b2[c0+2];
            float o3 = (v[4*m+3]-mu)*rstd*g2[c0+3] + b2[c0+3];
            uint2 u;
            u.x = (unsigned int)f2bf(o0) | ((unsigned int)f2bf(o1) << 16);
            u.y = (unsigned int)f2bf(o2) | ((unsigned int)f2bf(o3) << 16);
            *(uint2*)&hbn[rr][c0] = u;
        }
    }
    __syncthreads();

    // ---- fc1 (M=64,N=384,K=96) MFMA in two N-halves + bias + exact GELU -> h1s bf16 ----
#pragma unroll
    for (int half = 0; half < 2; ++half) {
        f32x4 acc[12];
#pragma unroll
        for (int t = 0; t < 12; ++t) acc[t] = (f32x4){0.f,0.f,0.f,0.f};
#pragma unroll
        for (int ks = 0; ks < 3; ++ks) {
            bf16x8 a = *(const bf16x8*)&hbn[wv*16 + lr][ks*32 + lk*8];
#pragma unroll
            for (int nt = 0; nt < 12; ++nt) {
                bf16x8 bf = *(const bf16x8*)(wsw + W1_OFF + (size_t)(half*192 + nt*16 + lr)*96 + ks*32 + lk*8);
                acc[nt] = __builtin_amdgcn_mfma_f32_16x16x32_bf16(a, bf, acc[nt], 0, 0, 0);
            }
        }
#pragma unroll
        for (int nt = 0; nt < 12; ++nt) {
            const int col = half*192 + nt*16 + lr;
            const float bias = bb1[col];
#pragma unroll
            for (int i = 0; i < 4; ++i) {
                const int rrow = wv*16 + lk*4 + i;
                const float t = acc[nt][i] + bias;
                h1s[rrow][col] = f2bf(0.5f*t*(1.f + erff(t*0.70710678118654752f)));
            }
        }
    }
    __syncthreads();

    // ---- fc2 (M=64,N=96,K=384) MFMA + bias + residual -> xio ----
    {
        f32x4 acc[6];
#pragma unroll
        for (int t = 0; t < 6; ++t) acc[t] = (f32x4){0.f,0.f,0.f,0.f};
#pragma unroll
        for (int ks = 0; ks < 12; ++ks) {
            bf16x8 a = *(const bf16x8*)&h1s[wv*16 + lr][ks*32 + lk*8];
#pragma unroll
            for (int nt = 0; nt < 6; ++nt) {
                bf16x8 bf = *(const bf16x8*)(wsw + W2_OFF + (size_t)(nt*16 + lr)*384 + ks*32 + lk*8);
                acc[nt] = __builtin_amdgcn_mfma_f32_16x16x32_bf16(a, bf, acc[nt], 0, 0, 0);
            }
        }
#pragma unroll
        for (int nt = 0; nt < 6; ++nt) {
            const int col = nt*16 + lr;
            const float bias = bb2[col];
#pragma unroll
            for (int i = 0; i < 4; ++i) {
                const int row = r0 + wv*16 + lk*4 + i;
                float* p = xio + (size_t)row*C_ + col;
                *p = acc[nt][i] + bias + *p;
            }
        }
    }
}

extern "C" void kernel_launch(void* const* d_in, const int* in_sizes, int n_in,
                              void* d_out, int out_size, void* d_ws, size_t ws_size,
                              hipStream_t stream) {
    const float* x    = (const float*)d_in[0];
    const float* n1g  = (const float*)d_in[1];
    const float* n1b  = (const float*)d_in[2];
    const float* qkvw = (const float*)d_in[3];
    const float* qkvb = (const float*)d_in[4];
    const float* rpbt = (const float*)d_in[5];
    const float* pw   = (const float*)d_in[6];
    const float* pb   = (const float*)d_in[7];
    const float* n2g  = (const float*)d_in[8];
    const float* n2b  = (const float*)d_in[9];
    const float* w1   = (const float*)d_in[10];
    const float* b1f  = (const float*)d_in[11];
    const float* w2   = (const float*)d_in[12];
    const float* b2f  = (const float*)d_in[13];
    float* outp = (float*)d_out;
    unsigned short* wsw = (unsigned short*)d_ws;

    k_conv<<<dim3((WTOT + 255)/256), dim3(256), 0, stream>>>(qkvw, pw, w1, w2, wsw);
    k_attn<<<dim3(4096), dim3(256), 0, stream>>>(x, n1g, n1b, wsw, qkvb, rpbt, pb, outp);
    k_mlp <<<dim3(4096), dim3(256), 0, stream>>>(outp, n2g, n2b, wsw, b1f, b2f);
}

// Round 7
// 546.816 us; speedup vs baseline: 4.3428x; 1.1098x over previous
//
#include <hip/hip_runtime.h>
#include <math.h>

#define B_IMG 64
#define H_ 64
#define W_ 64
#define L_ (H_*W_)
#define C_ 96
#define WSZ 8
#define SSZ 4
#define NH_ 4
#define HD_ 24
#define NT_ 64

// bf16 weight workspace layout (element offsets, 2B each)
#define QKVW_OFF 0
#define PROJW_OFF 27648     // 288*96
#define W1_OFF   36864      // +96*96
#define W2_OFF   73728      // +384*96
#define WTOT     110592     // +96*384

typedef short bf16x8 __attribute__((ext_vector_type(8)));
typedef float f32x4  __attribute__((ext_vector_type(4)));

__device__ __forceinline__ float bf2f(unsigned short u) {
    union { unsigned int i; float f; } c; c.i = ((unsigned int)u) << 16; return c.f;
}
__device__ __forceinline__ unsigned short f2bf(float f) {
    union { float f; unsigned int i; } c; c.f = f;
    return (unsigned short)((c.i + 0x7fffu + ((c.i >> 16) & 1u)) >> 16);  // RNE
}
__device__ __forceinline__ int reg_of(int ii, int jj, int whi, int wwi) {
    const int rh = (whi == 7) ? ((ii < SSZ) ? 1 : 2) : 0;
    const int rw = (wwi == 7) ? ((jj < SSZ) ? 1 : 2) : 0;
    return rh*3 + rw;
}

// ---------------- Kernel 0: convert weights fp32 -> bf16 into d_ws ----------------
__global__ void k_conv(const float* __restrict__ qkvw, const float* __restrict__ projw,
                       const float* __restrict__ w1, const float* __restrict__ w2,
                       unsigned short* __restrict__ ws16) {
    int i = blockIdx.x * 256 + threadIdx.x;
    if (i >= WTOT) return;
    float v;
    if (i < PROJW_OFF)      v = qkvw[i];
    else if (i < W1_OFF)    v = projw[i - PROJW_OFF];
    else if (i < W2_OFF)    v = w1[i - W1_OFF];
    else                    v = w2[i - W2_OFF];
    ws16[i] = f2bf(v);
}

// ---------------- Kernel 1: LN1 + shifted-window attention (full MFMA) + proj + residual ----------------
// 512 threads (8 waves) per window. LDS ~64.5KB -> 2 blocks/CU -> 16 waves/CU.
// Phase work split: P2/P4 split N across wave pairs; P3 splits M (q-rows) across wave pairs per head.
__global__ __launch_bounds__(512)
void k_attn(const float* __restrict__ x,
            const float* __restrict__ g1, const float* __restrict__ b1,
            const unsigned short* __restrict__ wsw,
            const float* __restrict__ qkvb,
            const float* __restrict__ rpbt,
            const float* __restrict__ projb,
            float* __restrict__ xmid)
{
    const int wid = blockIdx.x;
    const int b = wid >> 6, whi = (wid >> 3) & 7, wwi = wid & 7;
    const int tid = threadIdx.x;
    const int l = tid & 63, wv = tid >> 6;     // wv 0..7
    const int e = l & 15, g = l >> 4;          // MFMA lane coords

    __shared__ __align__(16) unsigned short hbn[NT_][104];   // LN-out bf16; later attn-out (13.3KB)
    __shared__ __align__(16) unsigned short qkps[NH_][4096]; // per head: Q[64][32] | K[64][32]; later P[64][64] swz (32KB)
    __shared__ __align__(16) unsigned short vt[NH_][2048];   // V^T [32][64] bf16, XOR-swizzled rows (16KB)
    __shared__ float rpbf[900];                              // rel-pos bias table (3.6KB)

    // ---- P0: zero qkps (K=32 MFMA needs k=24..31 == 0) + stage rpb ----
    {
        uint4* z = (uint4*)&qkps[0][0];
        for (int i = tid; i < 2048; i += 512) z[i] = (uint4){0,0,0,0};
        for (int i = tid; i < 900; i += 512) rpbf[i] = rpbt[i];
    }

    // ---- P1: LayerNorm -> hbn (bf16). 8 threads per row. ----
    {
        const int tok = tid >> 3, q = tid & 7;
        const int i = tok >> 3, j = tok & 7;
        const int sr = (whi*WSZ + i + SSZ) & (H_-1);
        const int sc = (wwi*WSZ + j + SSZ) & (W_-1);
        const float* row = x + ((size_t)b*L_ + sr*W_ + sc) * C_;
        float v[12];
        float s = 0.f, s2 = 0.f;
#pragma unroll
        for (int m = 0; m < 3; ++m) {
            float4 f = ((const float4*)row)[q + 8*m];
            v[4*m+0]=f.x; v[4*m+1]=f.y; v[4*m+2]=f.z; v[4*m+3]=f.w;
            s  += f.x+f.y+f.z+f.w;
            s2 += f.x*f.x+f.y*f.y+f.z*f.z+f.w*f.w;
        }
        s  += __shfl_xor(s, 1);  s  += __shfl_xor(s, 2);  s  += __shfl_xor(s, 4);
        s2 += __shfl_xor(s2, 1); s2 += __shfl_xor(s2, 2); s2 += __shfl_xor(s2, 4);
        const float mu = s * (1.f/96.f);
        const float rstd = rsqrtf(s2*(1.f/96.f) - mu*mu + 1e-5f);
#pragma unroll
        for (int m = 0; m < 3; ++m) {
            const int c0 = 4*(q + 8*m);
            float o0 = (v[4*m+0]-mu)*rstd*g1[c0+0] + b1[c0+0];
            float o1 = (v[4*m+1]-mu)*rstd*g1[c0+1] + b1[c0+1];
            float o2 = (v[4*m+2]-mu)*rstd*g1[c0+2] + b1[c0+2];
            float o3 = (v[4*m+3]-mu)*rstd*g1[c0+3] + b1[c0+3];
            uint2 u;
            u.x = (unsigned int)f2bf(o0) | ((unsigned int)f2bf(o1) << 16);
            u.y = (unsigned int)f2bf(o2) | ((unsigned int)f2bf(o3) << 16);
            *(uint2*)&hbn[tok][c0] = u;
        }
    }
    __syncthreads();

    // ---- P2: QKV GEMM via MFMA (M=64, N=288, K=96). wave = (M-tile wv&3, N-half wv>>2). ----
    {
        const int mt = wv & 3, nbase = (wv >> 2) * 9;
        f32x4 acc[9];
#pragma unroll
        for (int nt = 0; nt < 9; ++nt) acc[nt] = (f32x4){0.f,0.f,0.f,0.f};
#pragma unroll
        for (int ks = 0; ks < 3; ++ks) {
            bf16x8 a = *(const bf16x8*)&hbn[mt*16 + e][ks*32 + g*8];
#pragma unroll
            for (int ntl = 0; ntl < 9; ++ntl) {
                bf16x8 bw = *(const bf16x8*)(wsw + QKVW_OFF + (size_t)((nbase+ntl)*16 + e)*96 + ks*32 + g*8);
                acc[ntl] = __builtin_amdgcn_mfma_f32_16x16x32_bf16(a, bw, acc[ntl], 0, 0, 0);
            }
        }
#pragma unroll
        for (int ntl = 0; ntl < 9; ++ntl) {
            const int nt = nbase + ntl;              // wave-uniform
            const int col = nt*16 + e;
            const int seg = nt / 6;                  // 0:q 1:k 2:v (wave-uniform)
            const int cs  = col - seg*96;            // 0..95
            const int hh  = cs / 24;
            const int dd  = cs - hh*24;
            const float bias = qkvb[col];
#pragma unroll
            for (int i = 0; i < 4; ++i) {
                const int row = mt*16 + g*4 + i;     // token
                const float val = acc[ntl][i] + bias;
                if (seg == 0)      qkps[hh][row*32 + dd] = f2bf(val * 0.20412414523193154f);
                else if (seg == 1) qkps[hh][2048 + row*32 + dd] = f2bf(val);
                else               vt[hh][dd*64 + ((((row*2) ^ ((dd&7)<<4))) >> 1)] = f2bf(val);
            }
        }
    }
    __syncthreads();

    // ---- P3: attention via MFMA. wave = (head hd = wv&3, M-half mhalf = wv>>2). ----
    {
        const int hd = wv & 3, mhalf = wv >> 2;
        const unsigned short* qbase = &qkps[hd][0];
        const unsigned short* kbase = &qkps[hd][2048];
        unsigned short* psb = &qkps[hd][0];          // P[64][64] overlays Q|K after fragment loads

        // load ALL needed Q/K fragments into registers first (both waves of this head share region)
        bf16x8 qf[2], kf[4];
#pragma unroll
        for (int mtl = 0; mtl < 2; ++mtl) {
            const int mt = mhalf*2 + mtl;
            qf[mtl] = *(const bf16x8*)(qbase + (mt*16 + e)*32 + g*8);
        }
#pragma unroll
        for (int nt = 0; nt < 4; ++nt)
            kf[nt] = *(const bf16x8*)(kbase + (nt*16 + e)*32 + g*8);
        __syncthreads();   // all waves' Q/K fragment loads complete before anyone overlays P

        // QK^T: this wave's 32 q-rows x all 64 keys, K-dim 32 (24 + zero pad)
        f32x4 acc[2][4];
        {
            const f32x4 zz = (f32x4){0.f,0.f,0.f,0.f};
#pragma unroll
            for (int mtl = 0; mtl < 2; ++mtl)
#pragma unroll
                for (int nt = 0; nt < 4; ++nt)
                    acc[mtl][nt] = __builtin_amdgcn_mfma_f32_16x16x32_bf16(qf[mtl], kf[nt], zz, 0, 0, 0);
        }

        // bias + mask + row softmax + pack bf16 -> P (swizzled)
        const int j2 = e & 7, i2b = e >> 3;
        int rgc[4];
#pragma unroll
        for (int nt = 0; nt < 4; ++nt) rgc[nt] = reg_of(nt*2 + i2b, j2, whi, wwi);

#pragma unroll
        for (int mtl = 0; mtl < 2; ++mtl) {
#pragma unroll
            for (int ii = 0; ii < 4; ++ii) {
                const int r  = (mhalf*2 + mtl)*16 + g*4 + ii;   // query token
                const int i1 = r >> 3, j1 = r & 7;
                const int rg1 = reg_of(i1, j1, whi, wwi);
                const int cbase = ((i1 + 7 - i2b)*15 + (j1 - j2 + 7))*4 + hd;
                float sv[4];
#pragma unroll
                for (int nt = 0; nt < 4; ++nt) {
                    float t = acc[mtl][nt][ii] + rpbf[cbase - nt*120];
                    if (rg1 != rgc[nt]) t -= 100.f;
                    sv[nt] = t;
                }
                float m = fmaxf(fmaxf(sv[0], sv[1]), fmaxf(sv[2], sv[3]));
                m = fmaxf(m, __shfl_xor(m, 1)); m = fmaxf(m, __shfl_xor(m, 2));
                m = fmaxf(m, __shfl_xor(m, 4)); m = fmaxf(m, __shfl_xor(m, 8));
                float sum = 0.f;
#pragma unroll
                for (int nt = 0; nt < 4; ++nt) { sv[nt] = __expf(sv[nt] - m); sum += sv[nt]; }
                sum += __shfl_xor(sum, 1); sum += __shfl_xor(sum, 2);
                sum += __shfl_xor(sum, 4); sum += __shfl_xor(sum, 8);
                const float inv = 1.f / sum;
                const int swx = (r & 7) << 4;
#pragma unroll
                for (int nt = 0; nt < 4; ++nt) {
                    const int cbyte = (nt*16 + e)*2;
                    psb[r*64 + ((cbyte ^ swx) >> 1)] = f2bf(sv[nt] * inv);
                }
            }
        }
        // drain this wave's P writes before its own cross-lane P reads (PV reads own rows only)
        asm volatile("s_waitcnt lgkmcnt(0)" ::: "memory");

        // PV: O rows (this wave's 32) = P[rows][64] @ V ; B = V^T[32][64] swizzled
        f32x4 acc2[2][2];
#pragma unroll
        for (int mtl = 0; mtl < 2; ++mtl)
#pragma unroll
            for (int nt2 = 0; nt2 < 2; ++nt2) acc2[mtl][nt2] = (f32x4){0.f,0.f,0.f,0.f};
#pragma unroll
        for (int ks2 = 0; ks2 < 2; ++ks2) {
            bf16x8 pf[2], vf[2];
#pragma unroll
            for (int mtl = 0; mtl < 2; ++mtl) {
                const int rr = (mhalf*2 + mtl)*16 + e;
                const int gg = (ks2*4 + g) ^ (rr & 7);
                pf[mtl] = *(const bf16x8*)(psb + rr*64 + gg*8);
            }
#pragma unroll
            for (int nt2 = 0; nt2 < 2; ++nt2) {
                const int d = nt2*16 + e;
                const int gg = (ks2*4 + g) ^ (d & 7);
                vf[nt2] = *(const bf16x8*)(&vt[hd][0] + d*64 + gg*8);
            }
#pragma unroll
            for (int mtl = 0; mtl < 2; ++mtl)
#pragma unroll
                for (int nt2 = 0; nt2 < 2; ++nt2)
                    acc2[mtl][nt2] = __builtin_amdgcn_mfma_f32_16x16x32_bf16(pf[mtl], vf[nt2], acc2[mtl][nt2], 0, 0, 0);
        }
        // O -> hbn cols hd*24..+23
#pragma unroll
        for (int mtl = 0; mtl < 2; ++mtl) {
#pragma unroll
            for (int ii = 0; ii < 4; ++ii) {
                const int r = (mhalf*2 + mtl)*16 + g*4 + ii;
                hbn[r][hd*24 + e] = f2bf(acc2[mtl][0][ii]);
                if (e < 8) hbn[r][hd*24 + 16 + e] = f2bf(acc2[mtl][1][ii]);
            }
        }
    }
    __syncthreads();

    // ---- P4: proj via MFMA (M=64, N=96, K=96). wave = (M-tile wv&3, N-half wv>>2). ----
    {
        const int mt = wv & 3, nh = wv >> 2;
        f32x4 pacc[3];
#pragma unroll
        for (int nt = 0; nt < 3; ++nt) pacc[nt] = (f32x4){0.f,0.f,0.f,0.f};
#pragma unroll
        for (int ks = 0; ks < 3; ++ks) {
            bf16x8 a = *(const bf16x8*)&hbn[mt*16 + e][ks*32 + g*8];
#pragma unroll
            for (int nt = 0; nt < 3; ++nt) {
                const int col = nh*48 + nt*16 + e;
                bf16x8 bw = *(const bf16x8*)(wsw + PROJW_OFF + (size_t)col*96 + ks*32 + g*8);
                pacc[nt] = __builtin_amdgcn_mfma_f32_16x16x32_bf16(a, bw, pacc[nt], 0, 0, 0);
            }
        }
#pragma unroll
        for (int i = 0; i < 4; ++i) {
            const int n = mt*16 + g*4 + i;           // window token
            const int wi = n >> 3, wj = n & 7;
            const int sr = (whi*WSZ + wi + SSZ) & (H_-1);
            const int sc = (wwi*WSZ + wj + SSZ) & (W_-1);
            const size_t base = ((size_t)b*L_ + sr*W_ + sc)*C_;
#pragma unroll
            for (int nt = 0; nt < 3; ++nt) {
                const int c = nh*48 + nt*16 + e;
                xmid[base + c] = pacc[nt][i] + projb[c] + x[base + c];
            }
        }
    }
}

// ---------------- Kernel 2: LN2 + fc1 + GELU + fc2 + residual (MFMA bf16) ----------------
// 512 threads (8 waves), 64 rows. wave = (M-tile wv&3, N-part wv>>2).
__global__ __launch_bounds__(512)
void k_mlp(float* xio,
           const float* __restrict__ g2, const float* __restrict__ b2,
           const unsigned short* __restrict__ wsw,
           const float* __restrict__ bb1, const float* __restrict__ bb2)
{
    const int r0 = blockIdx.x * 64;
    const int tid = threadIdx.x;
    const int l = tid & 63, wv = tid >> 6;
    const int lr = l & 15, lk = l >> 4;

    __shared__ __align__(16) unsigned short hbn[64][120];   // LN2 out bf16 (15.4KB)
    __shared__ __align__(16) unsigned short h1s[64][392];   // gelu(fc1) bf16 (50.2KB)

    // ---- LN2 (8 threads/row) -> hbn bf16 ----
    {
        const int rr = tid >> 3, q = tid & 7;
        const float* row = xio + (size_t)(r0+rr)*C_;
        float v[12];
        float s = 0.f, s2 = 0.f;
#pragma unroll
        for (int m = 0; m < 3; ++m) {
            float4 f = ((const float4*)row)[q + 8*m];
            v[4*m+0]=f.x; v[4*m+1]=f.y; v[4*m+2]=f.z; v[4*m+3]=f.w;
            s  += f.x+f.y+f.z+f.w;
            s2 += f.x*f.x+f.y*f.y+f.z*f.z+f.w*f.w;
        }
        s  += __shfl_xor(s, 1);  s  += __shfl_xor(s, 2);  s  += __shfl_xor(s, 4);
        s2 += __shfl_xor(s2, 1); s2 += __shfl_xor(s2, 2); s2 += __shfl_xor(s2, 4);
        const float mu = s * (1.f/96.f);
        const float rstd = rsqrtf(s2*(1.f/96.f) - mu*mu + 1e-5f);
#pragma unroll
        for (int m = 0; m < 3; ++m) {
            const int c0 = 4*(q + 8*m);
            float o0 = (v[4*m+0]-mu)*rstd*g2[c0+0] + b2[c0+0];
            float o1 = (v[4*m+1]-mu)*rstd*g2[c0+1] + b2[c0+1];
            float o2 = (v[4*m+2]-mu)*rstd*g2[c0+2] + b2[c0+2];
            float o3 = (v[4*m+3]-mu)*rstd*g2[c0+3] + b2[c0+3];
            uint2 u;
            u.x = (unsigned int)f2bf(o0) | ((unsigned int)f2bf(o1) << 16);
            u.y = (unsigned int)f2bf(o2) | ((unsigned int)f2bf(o3) << 16);
            *(uint2*)&hbn[rr][c0] = u;
        }
    }
    __syncthreads();

    // ---- fc1 (M=64,N=384,K=96): wave = (mt, N-half). acc[12]. + bias + exact GELU -> h1s ----
    {
        const int mt = wv & 3, nh = wv >> 2;
        f32x4 acc[12];
#pragma unroll
        for (int t = 0; t < 12; ++t) acc[t] = (f32x4){0.f,0.f,0.f,0.f};
#pragma unroll
        for (int ks = 0; ks < 3; ++ks) {
            bf16x8 a = *(const bf16x8*)&hbn[mt*16 + lr][ks*32 + lk*8];
#pragma unroll
            for (int nt = 0; nt < 12; ++nt) {
                const int col = nh*192 + nt*16 + lr;
                bf16x8 bf = *(const bf16x8*)(wsw + W1_OFF + (size_t)col*96 + ks*32 + lk*8);
                acc[nt] = __builtin_amdgcn_mfma_f32_16x16x32_bf16(a, bf, acc[nt], 0, 0, 0);
            }
        }
#pragma unroll
        for (int nt = 0; nt < 12; ++nt) {
            const int col = nh*192 + nt*16 + lr;
            const float bias = bb1[col];
#pragma unroll
            for (int i = 0; i < 4; ++i) {
                const int rrow = mt*16 + lk*4 + i;
                const float t = acc[nt][i] + bias;
                h1s[rrow][col] = f2bf(0.5f*t*(1.f + erff(t*0.70710678118654752f)));
            }
        }
    }
    __syncthreads();

    // ---- fc2 (M=64,N=96,K=384): wave = (mt, N-half 48). acc[3]. + bias + residual -> xio ----
    {
        const int mt = wv & 3, nh = wv >> 2;
        f32x4 acc[3];
#pragma unroll
        for (int t = 0; t < 3; ++t) acc[t] = (f32x4){0.f,0.f,0.f,0.f};
#pragma unroll
        for (int ks = 0; ks < 12; ++ks) {
            bf16x8 a = *(const bf16x8*)&h1s[mt*16 + lr][ks*32 + lk*8];
#pragma unroll
            for (int nt = 0; nt < 3; ++nt) {
                const int col = nh*48 + nt*16 + lr;
                bf16x8 bf = *(const bf16x8*)(wsw + W2_OFF + (size_t)col*384 + ks*32 + lk*8);
                acc[nt] = __builtin_amdgcn_mfma_f32_16x16x32_bf16(a, bf, acc[nt], 0, 0, 0);
            }
        }
#pragma unroll
        for (int nt = 0; nt < 3; ++nt) {
            const int col = nh*48 + nt*16 + lr;
            const float bias = bb2[col];
#pragma unroll
            for (int i = 0; i < 4; ++i) {
                const int row = r0 + mt*16 + lk*4 + i;
                float* p = xio + (size_t)row*C_ + col;
                *p = acc[nt][i] + bias + *p;
            }
        }
    }
}

extern "C" void kernel_launch(void* const* d_in, const int* in_sizes, int n_in,
                              void* d_out, int out_size, void* d_ws, size_t ws_size,
                              hipStream_t stream) {
    const float* x    = (const float*)d_in[0];
    const float* n1g  = (const float*)d_in[1];
    const float* n1b  = (const float*)d_in[2];
    const float* qkvw = (const float*)d_in[3];
    const float* qkvb = (const float*)d_in[4];
    const float* rpbt = (const float*)d_in[5];
    const float* pw   = (const float*)d_in[6];
    const float* pb   = (const float*)d_in[7];
    const float* n2g  = (const float*)d_in[8];
    const float* n2b  = (const float*)d_in[9];
    const float* w1   = (const float*)d_in[10];
    const float* b1f  = (const float*)d_in[11];
    const float* w2   = (const float*)d_in[12];
    const float* b2f  = (const float*)d_in[13];
    float* outp = (float*)d_out;
    unsigned short* wsw = (unsigned short*)d_ws;

    k_conv<<<dim3((WTOT + 255)/256), dim3(256), 0, stream>>>(qkvw, pw, w1, w2, wsw);
    k_attn<<<dim3(4096), dim3(512), 0, stream>>>(x, n1g, n1b, wsw, qkvb, rpbt, pb, outp);
    k_mlp <<<dim3(4096), dim3(512), 0, stream>>>(outp, n2g, n2b, wsw, b1f, b2f);
}